// Round 2
// baseline (490.358 us; speedup 1.0000x reference)
//
#include <hip/hip_runtime.h>
#include <hip/hip_bf16.h>
#include <stdint.h>

// Problem constants (fixed by setup_inputs)
#define M_TOT 8192
#define N_TOT 4096
#define K_TOT 4096
#define GROUP 128

// Round-2 lesson: fp16 reference arrays arrive as FLOAT32 ("else float*" rule).
// Round-4 lesson: fused one-pass is barrier/latency-bound; two-pass wins.
// Round-5 lesson: XOR chunk swizzle on global side of global_load_lds ->
//   0 LDS bank conflicts (measured).
// Round-6 lesson: 256^2 8-phase + counted vmcnt: 806 -> 1106 TF, MfmaUtil 49%.
// Round-7 (this round): prefetch depth was the stall -- A(t+1) had only ~2-3
//   phases of cover vs ~900cy HBM latency. Triple-buffer A (160 KiB LDS total),
//   stage A(t+2)+B(t+2) during tile t, end-of-tile vmcnt(8) drains loads issued
//   a full tile earlier. vmcnt moved BEFORE the tile's last barrier (formal
//   cross-wave visibility, m201 placement). cast_x+dequant_w fused into prep.

using f32x4  = __attribute__((ext_vector_type(4))) float;
using bf16x8 = __attribute__((ext_vector_type(8))) __bf16;

typedef __attribute__((address_space(3))) void as3_void;
typedef const __attribute__((address_space(1))) void as1_void;

// ---------------- pass 1: fused prep (dequant blocks first, then cast) -------
// blocks [0, 4096):        dequant qweight -> Wt [N][K] bf16 (LDS transpose)
// blocks [4096, 20480):    cast x f32 -> bf16
__global__ __launch_bounds__(256) void prep(
    const float* __restrict__ x,
    const int*   __restrict__ qweight,  // [K/8, N]
    const int*   __restrict__ qzeros,   // [G, N/8]
    const float* __restrict__ scales,   // [G, N]
    const int*   __restrict__ g_idx,    // [K]
    __bf16* __restrict__ xb,            // [M, K]
    __bf16* __restrict__ Wt)            // [N, K]
{
    const int tid = threadIdx.x;
    if (blockIdx.x < 4096) {
        __shared__ __align__(16) unsigned short T[64 * 72];  // [64n][72k]
        const int k0 = (blockIdx.x & 63) * 64;
        const int n0 = (blockIdx.x >> 6) * 64;
        const int g  = g_idx[k0];       // 64-k tile sits in one group (64 | 128)

        #pragma unroll
        for (int i = 0; i < 2; ++i) {
            const int idx = tid + i * 256;  // 0..511
            const int r   = idx >> 6;       // 0..7  (8 k's each)
            const int n   = idx & 63;
            const int qi  = qweight[(size_t)((k0 >> 3) + r) * N_TOT + n0 + n];
            const int zi  = qzeros[g * (N_TOT / 8) + ((n0 + n) >> 3)];
            const float s = scales[g * N_TOT + n0 + n];
            const float zs = (float)(((zi >> ((n & 7) * 4)) & 0xF) + 1) * s;
            bf16x8 v;
            #pragma unroll
            for (int j = 0; j < 8; ++j)
                v[j] = (__bf16)((float)((qi >> (4 * j)) & 0xF) * s - zs);  // (w-z-1)*s
            *(bf16x8*)&T[n * 72 + r * 8] = v;
        }
        __syncthreads();

        const int n = tid >> 2;             // 0..63
        const int c = (tid & 3) * 16;       // 0,16,32,48
        const bf16x8 a = *(const bf16x8*)&T[n * 72 + c];
        const bf16x8 b = *(const bf16x8*)&T[n * 72 + c + 8];
        __bf16* dst = Wt + (size_t)(n0 + n) * K_TOT + k0 + c;
        *(bf16x8*)dst = a;
        *(bf16x8*)(dst + 8) = b;
    } else {
        const size_t t = (size_t)(blockIdx.x - 4096) * 256 + tid;
        const float4 f0 = *(const float4*)(x + t * 8);
        const float4 f1 = *(const float4*)(x + t * 8 + 4);
        bf16x8 v;
        v[0]=(__bf16)f0.x; v[1]=(__bf16)f0.y; v[2]=(__bf16)f0.z; v[3]=(__bf16)f0.w;
        v[4]=(__bf16)f1.x; v[5]=(__bf16)f1.y; v[6]=(__bf16)f1.z; v[7]=(__bf16)f1.w;
        *(bf16x8*)(xb + t * 8) = v;
    }
}

// ------- pass 2: 256^2 8-phase bf16 GEMM (B^T), A triple-buffered -------
#define GBM 256
#define GBN 256
#define GBK 64
#define NKT (K_TOT / GBK)   // 64

#define BAR() do { asm volatile("" ::: "memory"); \
                   __builtin_amdgcn_s_barrier();  \
                   asm volatile("" ::: "memory"); } while (0)
#define WAIT_LGKM0() asm volatile("s_waitcnt lgkmcnt(0)" ::: "memory")
#define WAIT_VM8()   asm volatile("s_waitcnt vmcnt(8)"   ::: "memory")
#define WAIT_VM0()   asm volatile("s_waitcnt vmcnt(0)"   ::: "memory")

// Phase q: read A-quadrant q from Abuf[qa], issue STAGE, barrier, lgkmcnt(0),
// 16 MFMA under setprio(1), TAIL (end-of-tile vmcnt before last barrier).
#define GPHASE(q, STAGE_STMT, TAIL_STMT)                                      \
    {                                                                         \
        bf16x8 av[2][2];                                                      \
        _Pragma("unroll")                                                     \
        for (int ks = 0; ks < 2; ++ks) {                                      \
            av[0][ks] = ldfrag(&Abuf[qa][0], wm, 2 * (q), ks);                \
            av[1][ks] = ldfrag(&Abuf[qa][0], wm, 2 * (q) + 1, ks);            \
        }                                                                     \
        STAGE_STMT;                                                           \
        BAR();                                                                \
        WAIT_LGKM0();                                                         \
        __builtin_amdgcn_s_setprio(1);                                        \
        _Pragma("unroll")                                                     \
        for (int ks = 0; ks < 2; ++ks)                                        \
            _Pragma("unroll")                                                 \
            for (int mtl = 0; mtl < 2; ++mtl)                                 \
                _Pragma("unroll")                                             \
                for (int nt = 0; nt < 4; ++nt)                                \
                    acc[2 * (q) + mtl][nt] =                                  \
                        __builtin_amdgcn_mfma_f32_16x16x32_bf16(              \
                            av[mtl][ks], bv[nt][ks], acc[2 * (q) + mtl][nt],  \
                            0, 0, 0);                                         \
        __builtin_amdgcn_s_setprio(0);                                        \
        TAIL_STMT;                                                            \
        BAR();                                                                \
    }

__global__ __launch_bounds__(512, 2) void gemm8p(
    const __bf16* __restrict__ xb,   // [M, K]
    const __bf16* __restrict__ Wt,   // [N, K]
    const float*  __restrict__ bias, // [N]
    float* __restrict__ out)         // [M, N]
{
    // A: 3 buffers (96 KiB), B: 2 buffers (64 KiB) -> 160 KiB (full CU LDS)
    __shared__ __align__(16) unsigned short Abuf[3][GBM * GBK];
    __shared__ __align__(16) unsigned short Bbuf[2][GBM * GBK];

    const int tid  = threadIdx.x;
    const int wid  = tid >> 6;
    const int lane = tid & 63;
    const int l15  = lane & 15;
    const int quad = lane >> 4;

    // XCD-aware bijective swizzle (nwg = 512, divisible by 8)
    int bid = blockIdx.x;
    bid = (bid & 7) * (512 >> 3) + (bid >> 3);
    const int tn = bid & (N_TOT / GBN - 1);   // 0..15
    const int tm = bid >> 4;                  // 0..31
    const int m0 = tm * GBM;
    const int n0 = tn * GBN;

    const int wm = (wid >> 2) * 128;  // 0 or 128 (M-wave)
    const int wn = (wid & 3) * 64;    // 0..192   (N-wave)

    f32x4 acc[8][4];
    #pragma unroll
    for (int i = 0; i < 8; ++i)
        #pragma unroll
        for (int j = 0; j < 4; ++j)
            acc[i][j] = (f32x4)0.f;

    // Stage one half-tile (128 rows x 64 k) into ldsb, half h.
    // 2 x global_load_lds (16B)/thread. Chunk c holds global k-chunk
    // (c&7)^(row&7): LDS dst lane-linear, swizzle applied on global src.
    auto stage = [&](unsigned short* ldsb, int h,
                     const __bf16* __restrict__ base, int row0, int kt) {
        #pragma unroll
        for (int j = 0; j < 2; ++j) {
            const int c  = j * 512 + tid;          // 0..1023 chunk id
            const int rl = c >> 3;                 // 0..127 row in half
            const int kc = (c & 7) ^ (rl & 7);     // XOR swizzle (global side)
            const __bf16* ga = base + (size_t)(row0 + h * 128 + rl) * K_TOT
                             + kt * GBK + kc * 8;
            __builtin_amdgcn_global_load_lds((as1_void*)ga,
                (as3_void*)&ldsb[h * 8192 + (j * 512 + wid * 64) * 8],
                16, 0, 0);
        }
    };
    auto ldfrag = [&](const unsigned short* ldsb, int wbase, int mt,
                      int ks) -> bf16x8 {
        const int r = wbase + mt * 16 + l15;
        return *(const bf16x8*)
            &ldsb[r * GBK + (((ks * 4 + quad) ^ (r & 7)) << 3)];
    };

    // Prologue: A(0),B(0),A(1),B(1) staged (16 loads); vmcnt(8) = tiles 0
    // landed, tile 1 (8 loads) still in flight.
    stage(&Abuf[0][0], 0, xb, m0, 0); stage(&Abuf[0][0], 1, xb, m0, 0);
    stage(&Bbuf[0][0], 0, Wt, n0, 0); stage(&Bbuf[0][0], 1, Wt, n0, 0);
    stage(&Abuf[1][0], 0, xb, m0, 1); stage(&Abuf[1][0], 1, xb, m0, 1);
    stage(&Bbuf[1][0], 0, Wt, n0, 1); stage(&Bbuf[1][0], 1, Wt, n0, 1);
    WAIT_VM8();
    BAR();

    bf16x8 bv[4][2];  // B frags held in regs across the whole K-tile

    int qa = 0;  // A buf for tile t
    int qs = 2;  // A buf for tile t+2 (held A(t-1), consumed by end of t-1)
    int p  = 0;  // B buf for tile t; B(t+2) also lands here (B(t) read at ph0)

    for (int t = 0; t < NKT; ++t) {
        // ---- phase 0: all 8 B-frags + A quadrant 0 (12 ds_read_b128) ----
        {
            #pragma unroll
            for (int nt = 0; nt < 4; ++nt)
                #pragma unroll
                for (int ks = 0; ks < 2; ++ks)
                    bv[nt][ks] = ldfrag(&Bbuf[p][0], wn, nt, ks);
            bf16x8 av[2][2];
            #pragma unroll
            for (int ks = 0; ks < 2; ++ks) {
                av[0][ks] = ldfrag(&Abuf[qa][0], wm, 0, ks);
                av[1][ks] = ldfrag(&Abuf[qa][0], wm, 1, ks);
            }
            if (t + 2 < NKT) stage(&Abuf[qs][0], 0, xb, m0, t + 2);
            BAR();
            WAIT_LGKM0();
            __builtin_amdgcn_s_setprio(1);
            #pragma unroll
            for (int ks = 0; ks < 2; ++ks)
                #pragma unroll
                for (int mtl = 0; mtl < 2; ++mtl)
                    #pragma unroll
                    for (int nt = 0; nt < 4; ++nt)
                        acc[mtl][nt] = __builtin_amdgcn_mfma_f32_16x16x32_bf16(
                            av[mtl][ks], bv[nt][ks], acc[mtl][nt], 0, 0, 0);
            __builtin_amdgcn_s_setprio(0);
            BAR();
        }
        // ---- phases 1-3: A quadrant + one half-tile stage each ----
        GPHASE(1, if (t + 2 < NKT) stage(&Abuf[qs][0], 1, xb, m0, t + 2), );
        GPHASE(2, if (t + 2 < NKT) stage(&Bbuf[p][0], 0, Wt, n0, t + 2), );
        GPHASE(3, if (t + 2 < NKT) stage(&Bbuf[p][0], 1, Wt, n0, t + 2),
               if (t < NKT - 2) { WAIT_VM8(); } else { WAIT_VM0(); });

        qa = (qa == 2) ? 0 : qa + 1;
        qs = (qs == 2) ? 0 : qs + 1;
        p ^= 1;
    }

    // epilogue: C/D layout col=lane&15, row=quad*4+reg (m89/m91-verified)
    #pragma unroll
    for (int nt = 0; nt < 4; ++nt) {
        const int col = n0 + wn + nt * 16 + l15;
        const float bb = bias[col];
        #pragma unroll
        for (int mt = 0; mt < 8; ++mt) {
            const int rowb = m0 + wm + mt * 16 + quad * 4;
            #pragma unroll
            for (int i = 0; i < 4; ++i)
                out[(size_t)(rowb + i) * N_TOT + col] = acc[mt][nt][i] + bb;
        }
    }
}

// ---------------- fallback: round-4 fused kernel (proven correct) ----------------
#define FBM 256
#define FBN 128
#define FBKP 72

__global__ __launch_bounds__(256, 2) void gptq_gemm_fused(
    const float* __restrict__ x, const int* __restrict__ qweight,
    const int* __restrict__ qzeros, const float* __restrict__ scales,
    const int* __restrict__ g_idx, const float* __restrict__ bias,
    float* __restrict__ out)
{
    __shared__ __align__(16) unsigned short As[FBM * FBKP];
    __shared__ __align__(16) unsigned short Bt[FBN * FBKP];

    const int tid  = threadIdx.x;
    const int wave = tid >> 6;
    const int lane = tid & 63;
    const int n0 = blockIdx.x * FBN;
    const int m0 = blockIdx.y * FBM;
    const int wm = (wave >> 1) * 64;
    const int wn = (wave & 1) * 64;
    const int l15  = lane & 15;
    const int quad = lane >> 4;

    f32x4 acc[2][4][4];
    #pragma unroll
    for (int mi = 0; mi < 2; ++mi)
        #pragma unroll
        for (int i = 0; i < 4; ++i)
            #pragma unroll
            for (int j = 0; j < 4; ++j)
                acc[mi][i][j] = (f32x4)0.f;

    const int nb  = tid & 31;
    const int r   = tid >> 5;
    const int zsh = (nb & 7) * 4;

    for (int kt = 0; kt < K_TOT / 64; ++kt) {
        const int k0 = kt * 64;
        #pragma unroll
        for (int i = 0; i < 8; ++i) {
            const int c   = tid + i * 256;
            const int row = c >> 3;
            const int cb  = (c & 7) << 3;
            const float* xp = x + (size_t)(m0 + row) * K_TOT + (k0 + cb);
            const float4 f0 = *(const float4*)xp;
            const float4 f1 = *(const float4*)(xp + 4);
            bf16x8 v;
            v[0]=(__bf16)f0.x; v[1]=(__bf16)f0.y; v[2]=(__bf16)f0.z; v[3]=(__bf16)f0.w;
            v[4]=(__bf16)f1.x; v[5]=(__bf16)f1.y; v[6]=(__bf16)f1.z; v[7]=(__bf16)f1.w;
            *(bf16x8*)&As[row * FBKP + cb] = v;
        }
        const int g    = g_idx[k0];
        const int qrow = (k0 >> 3) + r;
        #pragma unroll
        for (int dn = 0; dn < 4; ++dn) {
            const int n  = nb + dn * 32;
            const int qi = qweight[(size_t)qrow * N_TOT + (n0 + n)];
            const int zi = qzeros[g * (N_TOT / 8) + ((n0 + n) >> 3)];
            const float s = scales[g * N_TOT + (n0 + n)];
            const float zs = (float)(((zi >> zsh) & 0xF) + 1) * s;
            bf16x8 v;
            #pragma unroll
            for (int j = 0; j < 8; ++j)
                v[j] = (__bf16)((float)((qi >> (4 * j)) & 0xF) * s - zs);
            *(bf16x8*)&Bt[n * FBKP + r * 8] = v;
        }
        __syncthreads();
        #pragma unroll
        for (int ks = 0; ks < 2; ++ks) {
            bf16x8 bvv[4];
            #pragma unroll
            for (int nt = 0; nt < 4; ++nt)
                bvv[nt] = *(const bf16x8*)&Bt[(wn + nt * 16 + l15) * FBKP + ks * 32 + quad * 8];
            #pragma unroll
            for (int mi = 0; mi < 2; ++mi) {
                bf16x8 av[4];
                #pragma unroll
                for (int mt = 0; mt < 4; ++mt)
                    av[mt] = *(const bf16x8*)&As[(mi * 128 + wm + mt * 16 + l15) * FBKP + ks * 32 + quad * 8];
                #pragma unroll
                for (int mt = 0; mt < 4; ++mt)
                    #pragma unroll
                    for (int nt = 0; nt < 4; ++nt)
                        acc[mi][mt][nt] = __builtin_amdgcn_mfma_f32_16x16x32_bf16(
                            av[mt], bvv[nt], acc[mi][mt][nt], 0, 0, 0);
            }
        }
        __syncthreads();
    }
    #pragma unroll
    for (int mi = 0; mi < 2; ++mi)
        #pragma unroll
        for (int nt = 0; nt < 4; ++nt) {
            const int col = n0 + wn + nt * 16 + l15;
            const float bvv = bias[col];
            #pragma unroll
            for (int mt = 0; mt < 4; ++mt) {
                const int rowb = m0 + mi * 128 + wm + mt * 16 + quad * 4;
                #pragma unroll
                for (int i = 0; i < 4; ++i)
                    out[(size_t)(rowb + i) * N_TOT + col] = acc[mi][mt][nt][i] + bvv;
            }
        }
}

extern "C" void kernel_launch(void* const* d_in, const int* in_sizes, int n_in,
                              void* d_out, int out_size, void* d_ws, size_t ws_size,
                              hipStream_t stream) {
    const float* x  = (const float*)d_in[0];
    const int*   qw = (const int*)d_in[1];
    const int*   qz = (const int*)d_in[2];
    const float* sc = (const float*)d_in[3];
    const int*   gi = (const int*)d_in[4];
    const float* bs = (const float*)d_in[5];
    float* out = (float*)d_out;

    const size_t xb_bytes = (size_t)M_TOT * K_TOT * 2;   // 67,108,864
    const size_t wt_bytes = (size_t)N_TOT * K_TOT * 2;   // 33,554,432

    if (ws_size >= xb_bytes + wt_bytes) {
        __bf16* xb = (__bf16*)d_ws;
        __bf16* Wt = (__bf16*)((char*)d_ws + xb_bytes);
        const int cast_blocks = (M_TOT * K_TOT) / (256 * 8);   // 16384
        prep<<<dim3(4096 + cast_blocks), dim3(256), 0, stream>>>(
            x, qw, qz, sc, gi, xb, Wt);
        gemm8p<<<dim3((M_TOT / GBM) * (N_TOT / GBN)), dim3(512), 0, stream>>>(
            xb, Wt, bs, out);
    } else {
        gptq_gemm_fused<<<dim3(N_TOT / FBN, M_TOT / FBM), dim3(256), 0, stream>>>(
            x, qw, qz, sc, gi, bs, out);
    }
}

// Round 4
// 472.462 us; speedup vs baseline: 1.0379x; 1.0379x over previous
//
#include <hip/hip_runtime.h>
#include <hip/hip_bf16.h>
#include <stdint.h>

// Problem constants (fixed by setup_inputs)
#define M_TOT 8192
#define N_TOT 4096
#define K_TOT 4096
#define GROUP 128

// Round-2 lesson: fp16 reference arrays arrive as FLOAT32 ("else float*" rule).
// Round-4 lesson: fused one-pass is barrier/latency-bound; two-pass wins.
// Round-5 lesson: XOR chunk swizzle on global side of global_load_lds ->
//   0 LDS bank conflicts (measured).
// Round-6 lesson: 256^2 8-phase + counted vmcnt: 806 -> 1106 TF, MfmaUtil 49%.
// Round-7 lesson (REGRESSED, reverted): triple-buffer A with mod-3 rotation ->
//   runtime LDS bases defeat unroll/const-folding (VGPR 116->104, MfmaUtil 42.5).
//   Keep power-of-2 buf = t&1.  Kept from r7: end-of-tile vmcnt BEFORE the
//   final barrier (cross-wave DMA visibility fix).
// Round-8 lesson: __builtin_nontemporal_load needs a clang vector type, not
//   HIP float4 (HIP_vector_type class) -- load via ext_vector f32x4.
// Round-9 (this round, = round-8 intent): remove the blanket asm lgkmcnt(0)
//   per phase. Our ds_reads are compiler-visible; hipcc emits fine-grained
//   lgkmcnt(N) interleaved with MFMAs (m97 asm). The blanket drain serialized
//   [12 reads -> wait -> MFMA] every phase (~150cy x 8/tile = the 50% stall).
//   Also: nontemporal x loads in prep (x read once; preserve L3 for xb/Wt).

using f32x4  = __attribute__((ext_vector_type(4))) float;
using bf16x8 = __attribute__((ext_vector_type(8))) __bf16;

typedef __attribute__((address_space(3))) void as3_void;
typedef const __attribute__((address_space(1))) void as1_void;

// ---------------- pass 1: fused prep (dequant blocks first, then cast) -------
// blocks [0, 4096):        dequant qweight -> Wt [N][K] bf16 (LDS transpose)
// blocks [4096, 20480):    cast x f32 -> bf16
__global__ __launch_bounds__(256) void prep(
    const float* __restrict__ x,
    const int*   __restrict__ qweight,  // [K/8, N]
    const int*   __restrict__ qzeros,   // [G, N/8]
    const float* __restrict__ scales,   // [G, N]
    const int*   __restrict__ g_idx,    // [K]
    __bf16* __restrict__ xb,            // [M, K]
    __bf16* __restrict__ Wt)            // [N, K]
{
    const int tid = threadIdx.x;
    if (blockIdx.x < 4096) {
        __shared__ __align__(16) unsigned short T[64 * 72];  // [64n][72k]
        const int k0 = (blockIdx.x & 63) * 64;
        const int n0 = (blockIdx.x >> 6) * 64;
        const int g  = g_idx[k0];       // 64-k tile sits in one group (64 | 128)

        #pragma unroll
        for (int i = 0; i < 2; ++i) {
            const int idx = tid + i * 256;  // 0..511
            const int r   = idx >> 6;       // 0..7  (8 k's each)
            const int n   = idx & 63;
            const int qi  = qweight[(size_t)((k0 >> 3) + r) * N_TOT + n0 + n];
            const int zi  = qzeros[g * (N_TOT / 8) + ((n0 + n) >> 3)];
            const float s = scales[g * N_TOT + n0 + n];
            const float zs = (float)(((zi >> ((n & 7) * 4)) & 0xF) + 1) * s;
            bf16x8 v;
            #pragma unroll
            for (int j = 0; j < 8; ++j)
                v[j] = (__bf16)((float)((qi >> (4 * j)) & 0xF) * s - zs);  // (w-z-1)*s
            *(bf16x8*)&T[n * 72 + r * 8] = v;
        }
        __syncthreads();

        const int n = tid >> 2;             // 0..63
        const int c = (tid & 3) * 16;       // 0,16,32,48
        const bf16x8 a = *(const bf16x8*)&T[n * 72 + c];
        const bf16x8 b = *(const bf16x8*)&T[n * 72 + c + 8];
        __bf16* dst = Wt + (size_t)(n0 + n) * K_TOT + k0 + c;
        *(bf16x8*)dst = a;
        *(bf16x8*)(dst + 8) = b;
    } else {
        const size_t t = (size_t)(blockIdx.x - 4096) * 256 + tid;
        // nontemporal: x is read exactly once; don't pollute L3 (gemm wants
        // xb/Wt/out resident there). Use clang ext_vector type (HIP float4
        // is a class -- builtin rejects it).
        const f32x4 f0 = __builtin_nontemporal_load((const f32x4*)(x + t * 8));
        const f32x4 f1 = __builtin_nontemporal_load((const f32x4*)(x + t * 8) + 1);
        bf16x8 v;
        v[0]=(__bf16)f0.x; v[1]=(__bf16)f0.y; v[2]=(__bf16)f0.z; v[3]=(__bf16)f0.w;
        v[4]=(__bf16)f1.x; v[5]=(__bf16)f1.y; v[6]=(__bf16)f1.z; v[7]=(__bf16)f1.w;
        *(bf16x8*)(xb + t * 8) = v;
    }
}

// ------- pass 2: 256^2 8-phase bf16 GEMM (B^T), XOR-swizzled LDS -------
#define GBM 256
#define GBN 256
#define GBK 64
#define NKT (K_TOT / GBK)   // 64

#define BAR() do { asm volatile("" ::: "memory"); \
                   __builtin_amdgcn_s_barrier();  \
                   asm volatile("" ::: "memory"); } while (0)
#define WAIT_VM4()   asm volatile("s_waitcnt vmcnt(4)"   ::: "memory")
#define WAIT_VM0()   asm volatile("s_waitcnt vmcnt(0)"   ::: "memory")

// Phase q (q=1..3): read A-quadrant, issue one half-tile stage, barrier,
// 16 MFMA under setprio(1).  NO blanket lgkmcnt(0): compiler inserts
// fine-grained lgkmcnt(N) per MFMA operand (round-9 change).  TAIL carries
// the end-of-tile counted vmcnt (before the final barrier: cross-wave DMA
// visibility).
#define GPHASE(q, STAGE_STMT, TAIL_STMT)                                      \
    {                                                                         \
        bf16x8 av[2][2];                                                      \
        _Pragma("unroll")                                                     \
        for (int ks = 0; ks < 2; ++ks) {                                      \
            av[0][ks] = ldfrag(&Abuf[buf][0], wm, 2 * (q), ks);               \
            av[1][ks] = ldfrag(&Abuf[buf][0], wm, 2 * (q) + 1, ks);           \
        }                                                                     \
        STAGE_STMT;                                                           \
        BAR();                                                                \
        __builtin_amdgcn_s_setprio(1);                                        \
        _Pragma("unroll")                                                     \
        for (int ks = 0; ks < 2; ++ks)                                        \
            _Pragma("unroll")                                                 \
            for (int mtl = 0; mtl < 2; ++mtl)                                 \
                _Pragma("unroll")                                             \
                for (int nt = 0; nt < 4; ++nt)                                \
                    acc[2 * (q) + mtl][nt] =                                  \
                        __builtin_amdgcn_mfma_f32_16x16x32_bf16(              \
                            av[mtl][ks], bv[nt][ks], acc[2 * (q) + mtl][nt],  \
                            0, 0, 0);                                         \
        __builtin_amdgcn_s_setprio(0);                                        \
        TAIL_STMT;                                                            \
        BAR();                                                                \
    }

__global__ __launch_bounds__(512, 2) void gemm8p(
    const __bf16* __restrict__ xb,   // [M, K]
    const __bf16* __restrict__ Wt,   // [N, K]
    const float*  __restrict__ bias, // [N]
    float* __restrict__ out)         // [M, N]
{
    // 2 x A (64 KiB) + 2 x B (64 KiB) = 128 KiB; buf = t&1 (const-foldable)
    __shared__ __align__(16) unsigned short Abuf[2][GBM * GBK];
    __shared__ __align__(16) unsigned short Bbuf[2][GBM * GBK];

    const int tid  = threadIdx.x;
    const int wid  = tid >> 6;
    const int lane = tid & 63;
    const int l15  = lane & 15;
    const int quad = lane >> 4;

    // XCD-aware bijective swizzle (nwg = 512, divisible by 8)
    int bid = blockIdx.x;
    bid = (bid & 7) * (512 >> 3) + (bid >> 3);
    const int tn = bid & (N_TOT / GBN - 1);   // 0..15
    const int tm = bid >> 4;                  // 0..31
    const int m0 = tm * GBM;
    const int n0 = tn * GBN;

    const int wm = (wid >> 2) * 128;  // 0 or 128 (M-wave)
    const int wn = (wid & 3) * 64;    // 0..192   (N-wave)

    f32x4 acc[8][4];
    #pragma unroll
    for (int i = 0; i < 8; ++i)
        #pragma unroll
        for (int j = 0; j < 4; ++j)
            acc[i][j] = (f32x4)0.f;

    // Stage one half-tile (128 rows x 64 k) into ldsb, half h.
    // 2 x global_load_lds (16B)/thread. Chunk c holds global k-chunk
    // (c&7)^(row&7): LDS dst lane-linear, swizzle applied on global src.
    auto stage = [&](unsigned short* ldsb, int h,
                     const __bf16* __restrict__ base, int row0, int kt) {
        #pragma unroll
        for (int j = 0; j < 2; ++j) {
            const int c  = j * 512 + tid;          // 0..1023 chunk id
            const int rl = c >> 3;                 // 0..127 row in half
            const int kc = (c & 7) ^ (rl & 7);     // XOR swizzle (global side)
            const __bf16* ga = base + (size_t)(row0 + h * 128 + rl) * K_TOT
                             + kt * GBK + kc * 8;
            __builtin_amdgcn_global_load_lds((as1_void*)ga,
                (as3_void*)&ldsb[h * 8192 + (j * 512 + wid * 64) * 8],
                16, 0, 0);
        }
    };
    auto ldfrag = [&](const unsigned short* ldsb, int wbase, int mt,
                      int ks) -> bf16x8 {
        const int r = wbase + mt * 16 + l15;
        return *(const bf16x8*)
            &ldsb[r * GBK + (((ks * 4 + quad) ^ (r & 7)) << 3)];
    };

    // Prologue: A(0),B(0) -> buf0; B(1) -> buf1 (12 loads). vmcnt(4) =
    // A(0),B(0) landed; B(1) (4 loads) still in flight. A(1) staged in-loop.
    stage(&Abuf[0][0], 0, xb, m0, 0); stage(&Abuf[0][0], 1, xb, m0, 0);
    stage(&Bbuf[0][0], 0, Wt, n0, 0); stage(&Bbuf[0][0], 1, Wt, n0, 0);
    stage(&Bbuf[1][0], 0, Wt, n0, 1); stage(&Bbuf[1][0], 1, Wt, n0, 1);
    WAIT_VM4();
    BAR();

    bf16x8 bv[4][2];  // B frags held in regs across the whole K-tile

    for (int t = 0; t < NKT; ++t) {
        const int buf = t & 1;

        // ---- phase 0: all 8 B-frags + A quadrant 0 (12 ds_read_b128) ----
        {
            #pragma unroll
            for (int nt = 0; nt < 4; ++nt)
                #pragma unroll
                for (int ks = 0; ks < 2; ++ks)
                    bv[nt][ks] = ldfrag(&Bbuf[buf][0], wn, nt, ks);
            bf16x8 av[2][2];
            #pragma unroll
            for (int ks = 0; ks < 2; ++ks) {
                av[0][ks] = ldfrag(&Abuf[buf][0], wm, 0, ks);
                av[1][ks] = ldfrag(&Abuf[buf][0], wm, 1, ks);
            }
            if (t + 1 < NKT) stage(&Abuf[buf ^ 1][0], 0, xb, m0, t + 1);
            BAR();
            __builtin_amdgcn_s_setprio(1);
            #pragma unroll
            for (int ks = 0; ks < 2; ++ks)
                #pragma unroll
                for (int mtl = 0; mtl < 2; ++mtl)
                    #pragma unroll
                    for (int nt = 0; nt < 4; ++nt)
                        acc[mtl][nt] = __builtin_amdgcn_mfma_f32_16x16x32_bf16(
                            av[mtl][ks], bv[nt][ks], acc[mtl][nt], 0, 0, 0);
            __builtin_amdgcn_s_setprio(0);
            BAR();
        }
        // ---- phases 1-3: A quadrant + one half-tile stage each ----
        // B(t+2) -> Bbuf[buf] is legal: B(t) fully consumed at phase 0.
        GPHASE(1, if (t + 1 < NKT) stage(&Abuf[buf ^ 1][0], 1, xb, m0, t + 1), );
        GPHASE(2, if (t + 2 < NKT) stage(&Bbuf[buf][0], 0, Wt, n0, t + 2), );
        GPHASE(3, if (t + 2 < NKT) stage(&Bbuf[buf][0], 1, Wt, n0, t + 2),
               if (t < NKT - 2) { WAIT_VM4(); } else { WAIT_VM0(); });
    }

    // epilogue: C/D layout col=lane&15, row=quad*4+reg (m89/m91-verified)
    #pragma unroll
    for (int nt = 0; nt < 4; ++nt) {
        const int col = n0 + wn + nt * 16 + l15;
        const float bb = bias[col];
        #pragma unroll
        for (int mt = 0; mt < 8; ++mt) {
            const int rowb = m0 + wm + mt * 16 + quad * 4;
            #pragma unroll
            for (int i = 0; i < 4; ++i)
                out[(size_t)(rowb + i) * N_TOT + col] = acc[mt][nt][i] + bb;
        }
    }
}

// ---------------- fallback: round-4 fused kernel (proven correct) ----------------
#define FBM 256
#define FBN 128
#define FBKP 72

__global__ __launch_bounds__(256, 2) void gptq_gemm_fused(
    const float* __restrict__ x, const int* __restrict__ qweight,
    const int* __restrict__ qzeros, const float* __restrict__ scales,
    const int* __restrict__ g_idx, const float* __restrict__ bias,
    float* __restrict__ out)
{
    __shared__ __align__(16) unsigned short As[FBM * FBKP];
    __shared__ __align__(16) unsigned short Bt[FBN * FBKP];

    const int tid  = threadIdx.x;
    const int wave = tid >> 6;
    const int lane = tid & 63;
    const int n0 = blockIdx.x * FBN;
    const int m0 = blockIdx.y * FBM;
    const int wm = (wave >> 1) * 64;
    const int wn = (wave & 1) * 64;
    const int l15  = lane & 15;
    const int quad = lane >> 4;

    f32x4 acc[2][4][4];
    #pragma unroll
    for (int mi = 0; mi < 2; ++mi)
        #pragma unroll
        for (int i = 0; i < 4; ++i)
            #pragma unroll
            for (int j = 0; j < 4; ++j)
                acc[mi][i][j] = (f32x4)0.f;

    const int nb  = tid & 31;
    const int r   = tid >> 5;
    const int zsh = (nb & 7) * 4;

    for (int kt = 0; kt < K_TOT / 64; ++kt) {
        const int k0 = kt * 64;
        #pragma unroll
        for (int i = 0; i < 8; ++i) {
            const int c   = tid + i * 256;
            const int row = c >> 3;
            const int cb  = (c & 7) << 3;
            const float* xp = x + (size_t)(m0 + row) * K_TOT + (k0 + cb);
            const float4 f0 = *(const float4*)xp;
            const float4 f1 = *(const float4*)(xp + 4);
            bf16x8 v;
            v[0]=(__bf16)f0.x; v[1]=(__bf16)f0.y; v[2]=(__bf16)f0.z; v[3]=(__bf16)f0.w;
            v[4]=(__bf16)f1.x; v[5]=(__bf16)f1.y; v[6]=(__bf16)f1.z; v[7]=(__bf16)f1.w;
            *(bf16x8*)&As[row * FBKP + cb] = v;
        }
        const int g    = g_idx[k0];
        const int qrow = (k0 >> 3) + r;
        #pragma unroll
        for (int dn = 0; dn < 4; ++dn) {
            const int n  = nb + dn * 32;
            const int qi = qweight[(size_t)qrow * N_TOT + (n0 + n)];
            const int zi = qzeros[g * (N_TOT / 8) + ((n0 + n) >> 3)];
            const float s = scales[g * N_TOT + (n0 + n)];
            const float zs = (float)(((zi >> zsh) & 0xF) + 1) * s;
            bf16x8 v;
            #pragma unroll
            for (int j = 0; j < 8; ++j)
                v[j] = (__bf16)((float)((qi >> (4 * j)) & 0xF) * s - zs);
            *(bf16x8*)&Bt[n * FBKP + r * 8] = v;
        }
        __syncthreads();
        #pragma unroll
        for (int ks = 0; ks < 2; ++ks) {
            bf16x8 bvv[4];
            #pragma unroll
            for (int nt = 0; nt < 4; ++nt)
                bvv[nt] = *(const bf16x8*)&Bt[(wn + nt * 16 + l15) * FBKP + ks * 32 + quad * 8];
            #pragma unroll
            for (int mi = 0; mi < 2; ++mi) {
                bf16x8 av[4];
                #pragma unroll
                for (int mt = 0; mt < 4; ++mt)
                    av[mt] = *(const bf16x8*)&As[(mi * 128 + wm + mt * 16 + l15) * FBKP + ks * 32 + quad * 8];
                #pragma unroll
                for (int mt = 0; mt < 4; ++mt)
                    #pragma unroll
                    for (int nt = 0; nt < 4; ++nt)
                        acc[mi][mt][nt] = __builtin_amdgcn_mfma_f32_16x16x32_bf16(
                            av[mt], bvv[nt], acc[mi][mt][nt], 0, 0, 0);
            }
        }
        __syncthreads();
    }
    #pragma unroll
    for (int mi = 0; mi < 2; ++mi)
        #pragma unroll
        for (int nt = 0; nt < 4; ++nt) {
            const int col = n0 + wn + nt * 16 + l15;
            const float bvv = bias[col];
            #pragma unroll
            for (int mt = 0; mt < 4; ++mt) {
                const int rowb = m0 + mi * 128 + wm + mt * 16 + quad * 4;
                #pragma unroll
                for (int i = 0; i < 4; ++i)
                    out[(size_t)(rowb + i) * N_TOT + col] = acc[mi][mt][nt][i] + bvv;
            }
        }
}

extern "C" void kernel_launch(void* const* d_in, const int* in_sizes, int n_in,
                              void* d_out, int out_size, void* d_ws, size_t ws_size,
                              hipStream_t stream) {
    const float* x  = (const float*)d_in[0];
    const int*   qw = (const int*)d_in[1];
    const int*   qz = (const int*)d_in[2];
    const float* sc = (const float*)d_in[3];
    const int*   gi = (const int*)d_in[4];
    const float* bs = (const float*)d_in[5];
    float* out = (float*)d_out;

    const size_t xb_bytes = (size_t)M_TOT * K_TOT * 2;   // 67,108,864
    const size_t wt_bytes = (size_t)N_TOT * K_TOT * 2;   // 33,554,432

    if (ws_size >= xb_bytes + wt_bytes) {
        __bf16* xb = (__bf16*)d_ws;
        __bf16* Wt = (__bf16*)((char*)d_ws + xb_bytes);
        const int cast_blocks = (M_TOT * K_TOT) / (256 * 8);   // 16384
        prep<<<dim3(4096 + cast_blocks), dim3(256), 0, stream>>>(
            x, qw, qz, sc, gi, xb, Wt);
        gemm8p<<<dim3((M_TOT / GBM) * (N_TOT / GBN)), dim3(512), 0, stream>>>(
            xb, Wt, bs, out);
    } else {
        gptq_gemm_fused<<<dim3(N_TOT / FBN, M_TOT / FBM), dim3(256), 0, stream>>>(
            x, qw, qz, sc, gi, bs, out);
    }
}

// Round 5
// 458.033 us; speedup vs baseline: 1.0706x; 1.0315x over previous
//
#include <hip/hip_runtime.h>
#include <hip/hip_bf16.h>
#include <stdint.h>

// Problem constants (fixed by setup_inputs)
#define M_TOT 8192
#define N_TOT 4096
#define K_TOT 4096
#define GROUP 128

// Round-2 lesson: fp16 reference arrays arrive as FLOAT32 ("else float*" rule).
// Round-4 lesson: fused one-pass is barrier/latency-bound; two-pass wins.
// Round-5 lesson: XOR chunk swizzle on global side of global_load_lds ->
//   0 LDS bank conflicts (measured).
// Round-6 lesson: 256^2 8-phase + counted vmcnt: 806 -> 1106 TF, MfmaUtil 49%
//   (this r1 schedule = 249us gemm = best measured; treat as golden base).
// Round-7 lesson (REGRESSED): mod-3 triple-buffer -> runtime LDS bases defeat
//   const-folding. Keep buf = t&1.
// Round-9 lesson (REGRESSED): removing blanket lgkmcnt(0) + vmcnt-before-
//   final-barrier -> 280us / 43% (= r2's 286/42.5). lgkm0 removal is NOT the
//   lever; r1's exact wait pattern restored (lgkm0 after BAR, end-of-tile
//   vmcnt AFTER the final barrier).
// Round-10 (this round): deep A-prefetch. r1's stall: end-of-tile vmcnt(4)
//   forces A(t+1) (issued ph0/ph1 of t, 2.5-3.5 phases = ~500cy earlier) to
//   land vs ~900cy HBM latency -> ~400cy stall/tile = the missing MfmaUtil.
//   Fix: pipeline A-quadrant ds_reads one phase ahead (ph0:q0+q1, ph1:q2,
//   ph2:q3) so Abuf[buf] is fully read by end of ph2; stage A(t+2) into the
//   SAME buf at ph3 (B already does this at ph1/ph2). All 8 loads/tile are
//   then for t+2 and the end-of-tile wait is vmcnt(8) -> never stalls.

using f32x4  = __attribute__((ext_vector_type(4))) float;
using bf16x8 = __attribute__((ext_vector_type(8))) __bf16;

typedef __attribute__((address_space(3))) void as3_void;
typedef const __attribute__((address_space(1))) void as1_void;

// ---------------- pass 1: fused prep (dequant blocks first, then cast) -------
// blocks [0, 4096):        dequant qweight -> Wt [N][K] bf16 (LDS transpose)
// blocks [4096, 20480):    cast x f32 -> bf16
__global__ __launch_bounds__(256) void prep(
    const float* __restrict__ x,
    const int*   __restrict__ qweight,  // [K/8, N]
    const int*   __restrict__ qzeros,   // [G, N/8]
    const float* __restrict__ scales,   // [G, N]
    const int*   __restrict__ g_idx,    // [K]
    __bf16* __restrict__ xb,            // [M, K]
    __bf16* __restrict__ Wt)            // [N, K]
{
    const int tid = threadIdx.x;
    if (blockIdx.x < 4096) {
        __shared__ __align__(16) unsigned short T[64 * 72];  // [64n][72k]
        const int k0 = (blockIdx.x & 63) * 64;
        const int n0 = (blockIdx.x >> 6) * 64;
        const int g  = g_idx[k0];       // 64-k tile sits in one group (64 | 128)

        #pragma unroll
        for (int i = 0; i < 2; ++i) {
            const int idx = tid + i * 256;  // 0..511
            const int r   = idx >> 6;       // 0..7  (8 k's each)
            const int n   = idx & 63;
            const int qi  = qweight[(size_t)((k0 >> 3) + r) * N_TOT + n0 + n];
            const int zi  = qzeros[g * (N_TOT / 8) + ((n0 + n) >> 3)];
            const float s = scales[g * N_TOT + n0 + n];
            const float zs = (float)(((zi >> ((n & 7) * 4)) & 0xF) + 1) * s;
            bf16x8 v;
            #pragma unroll
            for (int j = 0; j < 8; ++j)
                v[j] = (__bf16)((float)((qi >> (4 * j)) & 0xF) * s - zs);  // (w-z-1)*s
            *(bf16x8*)&T[n * 72 + r * 8] = v;
        }
        __syncthreads();

        const int n = tid >> 2;             // 0..63
        const int c = (tid & 3) * 16;       // 0,16,32,48
        const bf16x8 a = *(const bf16x8*)&T[n * 72 + c];
        const bf16x8 b = *(const bf16x8*)&T[n * 72 + c + 8];
        __bf16* dst = Wt + (size_t)(n0 + n) * K_TOT + k0 + c;
        *(bf16x8*)dst = a;
        *(bf16x8*)(dst + 8) = b;
    } else {
        const size_t t = (size_t)(blockIdx.x - 4096) * 256 + tid;
        // nontemporal: x is read exactly once; don't pollute L3.
        const f32x4 f0 = __builtin_nontemporal_load((const f32x4*)(x + t * 8));
        const f32x4 f1 = __builtin_nontemporal_load((const f32x4*)(x + t * 8) + 1);
        bf16x8 v;
        v[0]=(__bf16)f0.x; v[1]=(__bf16)f0.y; v[2]=(__bf16)f0.z; v[3]=(__bf16)f0.w;
        v[4]=(__bf16)f1.x; v[5]=(__bf16)f1.y; v[6]=(__bf16)f1.z; v[7]=(__bf16)f1.w;
        *(bf16x8*)(xb + t * 8) = v;
    }
}

// ------- pass 2: 256^2 8-phase bf16 GEMM (B^T), XOR-swizzled LDS -------
#define GBM 256
#define GBN 256
#define GBK 64
#define NKT (K_TOT / GBK)   // 64

#define BAR() do { asm volatile("" ::: "memory"); \
                   __builtin_amdgcn_s_barrier();  \
                   asm volatile("" ::: "memory"); } while (0)
#define WAIT_LGKM0() asm volatile("s_waitcnt lgkmcnt(0)" ::: "memory")
#define WAIT_VM8()   asm volatile("s_waitcnt vmcnt(8)"   ::: "memory")
#define WAIT_VM0()   asm volatile("s_waitcnt vmcnt(0)"   ::: "memory")

__global__ __launch_bounds__(512, 2) void gemm8p(
    const __bf16* __restrict__ xb,   // [M, K]
    const __bf16* __restrict__ Wt,   // [N, K]
    const float*  __restrict__ bias, // [N]
    float* __restrict__ out)         // [M, N]
{
    // [buf][mat: 0=A,1=B][256 rows * 64 k] ushort = 128 KiB total
    __shared__ __align__(16) unsigned short LDS[2][2][GBM * GBK];

    const int tid  = threadIdx.x;
    const int wid  = tid >> 6;
    const int lane = tid & 63;
    const int l15  = lane & 15;
    const int quad = lane >> 4;

    // XCD-aware bijective swizzle (nwg = 512, divisible by 8)
    int bid = blockIdx.x;
    bid = (bid & 7) * (512 >> 3) + (bid >> 3);
    const int tn = bid & (N_TOT / GBN - 1);   // 0..15
    const int tm = bid >> 4;                  // 0..31
    const int m0 = tm * GBM;
    const int n0 = tn * GBN;

    const int wm = (wid >> 2) * 128;  // 0 or 128 (M-wave)
    const int wn = (wid & 3) * 64;    // 0..192   (N-wave)

    f32x4 acc[8][4];
    #pragma unroll
    for (int i = 0; i < 8; ++i)
        #pragma unroll
        for (int j = 0; j < 4; ++j)
            acc[i][j] = (f32x4)0.f;

    // Stage one half-tile (128 rows x 64 k) into LDS[bf][mat], half h.
    // 2 x global_load_lds (16B)/thread. Chunk c holds global k-chunk
    // (c&7)^(row&7): LDS dst lane-linear, swizzle applied on global src.
    auto stage = [&](int bf, int mat, int h,
                     const __bf16* __restrict__ base, int row0, int kt) {
        #pragma unroll
        for (int j = 0; j < 2; ++j) {
            const int c  = j * 512 + tid;          // 0..1023 chunk id
            const int rl = c >> 3;                 // 0..127 row in half
            const int kc = (c & 7) ^ (rl & 7);     // XOR swizzle (global side)
            const __bf16* ga = base + (size_t)(row0 + h * 128 + rl) * K_TOT
                             + kt * GBK + kc * 8;
            __builtin_amdgcn_global_load_lds((as1_void*)ga,
                (as3_void*)&LDS[bf][mat][h * 8192 + (j * 512 + wid * 64) * 8],
                16, 0, 0);
        }
    };
    auto ldfrag = [&](int bf, int mat, int wbase, int mt, int ks) -> bf16x8 {
        const int r = wbase + mt * 16 + l15;
        return *(const bf16x8*)
            &LDS[bf][mat][r * GBK + (((ks * 4 + quad) ^ (r & 7)) << 3)];
    };

    // Prologue: tiles 0 and 1 fully staged (16 loads). vmcnt(8) = tile 0
    // landed; tile 1 (8 loads) still in flight.
    stage(0, 0, 0, xb, m0, 0); stage(0, 0, 1, xb, m0, 0);
    stage(0, 1, 0, Wt, n0, 0); stage(0, 1, 1, Wt, n0, 0);
    stage(1, 0, 0, xb, m0, 1); stage(1, 0, 1, xb, m0, 1);
    stage(1, 1, 0, Wt, n0, 1); stage(1, 1, 1, Wt, n0, 1);
    WAIT_VM8();
    BAR();

    bf16x8 bv[4][2];              // B frags, whole K-tile in regs
    bf16x8 avA[2][2], avB[2][2];  // A quadrant ping-pong (read 1 phase ahead)

    for (int t = 0; t < NKT; ++t) {
        const int buf = t & 1;

        // ---- phase 0: 8 B-frags + A quadrants 0 AND 1 (16 ds_read_b128) ----
        {
            #pragma unroll
            for (int nt = 0; nt < 4; ++nt)
                #pragma unroll
                for (int ks = 0; ks < 2; ++ks)
                    bv[nt][ks] = ldfrag(buf, 1, wn, nt, ks);
            #pragma unroll
            for (int ks = 0; ks < 2; ++ks) {
                avA[0][ks] = ldfrag(buf, 0, wm, 0, ks);
                avA[1][ks] = ldfrag(buf, 0, wm, 1, ks);
                avB[0][ks] = ldfrag(buf, 0, wm, 2, ks);  // q1 prefetch
                avB[1][ks] = ldfrag(buf, 0, wm, 3, ks);
            }
            BAR();
            WAIT_LGKM0();
            __builtin_amdgcn_s_setprio(1);
            #pragma unroll
            for (int ks = 0; ks < 2; ++ks)
                #pragma unroll
                for (int mtl = 0; mtl < 2; ++mtl)
                    #pragma unroll
                    for (int nt = 0; nt < 4; ++nt)
                        acc[mtl][nt] = __builtin_amdgcn_mfma_f32_16x16x32_bf16(
                            avA[mtl][ks], bv[nt][ks], acc[mtl][nt], 0, 0, 0);
            __builtin_amdgcn_s_setprio(0);
            BAR();
        }
        // ---- phase 1: MFMA q1 (avB); read q2 -> avA; stage B(t+2)h0 ----
        {
            #pragma unroll
            for (int ks = 0; ks < 2; ++ks) {
                avA[0][ks] = ldfrag(buf, 0, wm, 4, ks);
                avA[1][ks] = ldfrag(buf, 0, wm, 5, ks);
            }
            if (t + 2 < NKT) stage(buf, 1, 0, Wt, n0, t + 2);
            BAR();
            WAIT_LGKM0();
            __builtin_amdgcn_s_setprio(1);
            #pragma unroll
            for (int ks = 0; ks < 2; ++ks)
                #pragma unroll
                for (int mtl = 0; mtl < 2; ++mtl)
                    #pragma unroll
                    for (int nt = 0; nt < 4; ++nt)
                        acc[2 + mtl][nt] = __builtin_amdgcn_mfma_f32_16x16x32_bf16(
                            avB[mtl][ks], bv[nt][ks], acc[2 + mtl][nt], 0, 0, 0);
            __builtin_amdgcn_s_setprio(0);
            BAR();
        }
        // ---- phase 2: MFMA q2 (avA); read q3 -> avB; stage B(t+2)h1 ----
        {
            #pragma unroll
            for (int ks = 0; ks < 2; ++ks) {
                avB[0][ks] = ldfrag(buf, 0, wm, 6, ks);
                avB[1][ks] = ldfrag(buf, 0, wm, 7, ks);
            }
            if (t + 2 < NKT) stage(buf, 1, 1, Wt, n0, t + 2);
            BAR();
            WAIT_LGKM0();
            __builtin_amdgcn_s_setprio(1);
            #pragma unroll
            for (int ks = 0; ks < 2; ++ks)
                #pragma unroll
                for (int mtl = 0; mtl < 2; ++mtl)
                    #pragma unroll
                    for (int nt = 0; nt < 4; ++nt)
                        acc[4 + mtl][nt] = __builtin_amdgcn_mfma_f32_16x16x32_bf16(
                            avA[mtl][ks], bv[nt][ks], acc[4 + mtl][nt], 0, 0, 0);
            __builtin_amdgcn_s_setprio(0);
            BAR();
        }
        // ---- phase 3: MFMA q3 (avB); stage A(t+2) h0+h1 (Abuf[buf] fully
        //      consumed as of ph2's barrier) ----
        {
            if (t + 2 < NKT) {
                stage(buf, 0, 0, xb, m0, t + 2);
                stage(buf, 0, 1, xb, m0, t + 2);
            }
            BAR();
            WAIT_LGKM0();
            __builtin_amdgcn_s_setprio(1);
            #pragma unroll
            for (int ks = 0; ks < 2; ++ks)
                #pragma unroll
                for (int mtl = 0; mtl < 2; ++mtl)
                    #pragma unroll
                    for (int nt = 0; nt < 4; ++nt)
                        acc[6 + mtl][nt] = __builtin_amdgcn_mfma_f32_16x16x32_bf16(
                            avB[mtl][ks], bv[nt][ks], acc[6 + mtl][nt], 0, 0, 0);
            __builtin_amdgcn_s_setprio(0);
            BAR();
        }
        // End-of-tile: all 8 loads issued this tile are for t+2; vmcnt(8)
        // only requires pre-t loads (issued >=4.5 phases ago) complete ->
        // effectively stall-free. Drain at the tail. (r1 placement: after
        // the final barrier.)
        if (t < NKT - 2) { WAIT_VM8(); } else { WAIT_VM0(); }
    }

    // epilogue: C/D layout col=lane&15, row=quad*4+reg (m89/m91-verified)
    #pragma unroll
    for (int nt = 0; nt < 4; ++nt) {
        const int col = n0 + wn + nt * 16 + l15;
        const float bb = bias[col];
        #pragma unroll
        for (int mt = 0; mt < 8; ++mt) {
            const int rowb = m0 + wm + mt * 16 + quad * 4;
            #pragma unroll
            for (int i = 0; i < 4; ++i)
                out[(size_t)(rowb + i) * N_TOT + col] = acc[mt][nt][i] + bb;
        }
    }
}

// ---------------- fallback: round-4 fused kernel (proven correct) ----------------
#define FBM 256
#define FBN 128
#define FBKP 72

__global__ __launch_bounds__(256, 2) void gptq_gemm_fused(
    const float* __restrict__ x, const int* __restrict__ qweight,
    const int* __restrict__ qzeros, const float* __restrict__ scales,
    const int* __restrict__ g_idx, const float* __restrict__ bias,
    float* __restrict__ out)
{
    __shared__ __align__(16) unsigned short As[FBM * FBKP];
    __shared__ __align__(16) unsigned short Bt[FBN * FBKP];

    const int tid  = threadIdx.x;
    const int wave = tid >> 6;
    const int lane = tid & 63;
    const int n0 = blockIdx.x * FBN;
    const int m0 = blockIdx.y * FBM;
    const int wm = (wave >> 1) * 64;
    const int wn = (wave & 1) * 64;
    const int l15  = lane & 15;
    const int quad = lane >> 4;

    f32x4 acc[2][4][4];
    #pragma unroll
    for (int mi = 0; mi < 2; ++mi)
        #pragma unroll
        for (int i = 0; i < 4; ++i)
            #pragma unroll
            for (int j = 0; j < 4; ++j)
                acc[mi][i][j] = (f32x4)0.f;

    const int nb  = tid & 31;
    const int r   = tid >> 5;
    const int zsh = (nb & 7) * 4;

    for (int kt = 0; kt < K_TOT / 64; ++kt) {
        const int k0 = kt * 64;
        #pragma unroll
        for (int i = 0; i < 8; ++i) {
            const int c   = tid + i * 256;
            const int row = c >> 3;
            const int cb  = (c & 7) << 3;
            const float* xp = x + (size_t)(m0 + row) * K_TOT + (k0 + cb);
            const float4 f0 = *(const float4*)xp;
            const float4 f1 = *(const float4*)(xp + 4);
            bf16x8 v;
            v[0]=(__bf16)f0.x; v[1]=(__bf16)f0.y; v[2]=(__bf16)f0.z; v[3]=(__bf16)f0.w;
            v[4]=(__bf16)f1.x; v[5]=(__bf16)f1.y; v[6]=(__bf16)f1.z; v[7]=(__bf16)f1.w;
            *(bf16x8*)&As[row * FBKP + cb] = v;
        }
        const int g    = g_idx[k0];
        const int qrow = (k0 >> 3) + r;
        #pragma unroll
        for (int dn = 0; dn < 4; ++dn) {
            const int n  = nb + dn * 32;
            const int qi = qweight[(size_t)qrow * N_TOT + (n0 + n)];
            const int zi = qzeros[g * (N_TOT / 8) + ((n0 + n) >> 3)];
            const float s = scales[g * N_TOT + (n0 + n)];
            const float zs = (float)(((zi >> zsh) & 0xF) + 1) * s;
            bf16x8 v;
            #pragma unroll
            for (int j = 0; j < 8; ++j)
                v[j] = (__bf16)((float)((qi >> (4 * j)) & 0xF) * s - zs);
            *(bf16x8*)&Bt[n * FBKP + r * 8] = v;
        }
        __syncthreads();
        #pragma unroll
        for (int ks = 0; ks < 2; ++ks) {
            bf16x8 bvv[4];
            #pragma unroll
            for (int nt = 0; nt < 4; ++nt)
                bvv[nt] = *(const bf16x8*)&Bt[(wn + nt * 16 + l15) * FBKP + ks * 32 + quad * 8];
            #pragma unroll
            for (int mi = 0; mi < 2; ++mi) {
                bf16x8 av[4];
                #pragma unroll
                for (int mt = 0; mt < 4; ++mt)
                    av[mt] = *(const bf16x8*)&As[(mi * 128 + wm + mt * 16 + l15) * FBKP + ks * 32 + quad * 8];
                #pragma unroll
                for (int mt = 0; mt < 4; ++mt)
                    #pragma unroll
                    for (int nt = 0; nt < 4; ++nt)
                        acc[mi][mt][nt] = __builtin_amdgcn_mfma_f32_16x16x32_bf16(
                            av[mt], bvv[nt], acc[mi][mt][nt], 0, 0, 0);
            }
        }
        __syncthreads();
    }
    #pragma unroll
    for (int mi = 0; mi < 2; ++mi)
        #pragma unroll
        for (int nt = 0; nt < 4; ++nt) {
            const int col = n0 + wn + nt * 16 + l15;
            const float bvv = bias[col];
            #pragma unroll
            for (int mt = 0; mt < 4; ++mt) {
                const int rowb = m0 + mi * 128 + wm + mt * 16 + quad * 4;
                #pragma unroll
                for (int i = 0; i < 4; ++i)
                    out[(size_t)(rowb + i) * N_TOT + col] = acc[mi][mt][nt][i] + bvv;
            }
        }
}

extern "C" void kernel_launch(void* const* d_in, const int* in_sizes, int n_in,
                              void* d_out, int out_size, void* d_ws, size_t ws_size,
                              hipStream_t stream) {
    const float* x  = (const float*)d_in[0];
    const int*   qw = (const int*)d_in[1];
    const int*   qz = (const int*)d_in[2];
    const float* sc = (const float*)d_in[3];
    const int*   gi = (const int*)d_in[4];
    const float* bs = (const float*)d_in[5];
    float* out = (float*)d_out;

    const size_t xb_bytes = (size_t)M_TOT * K_TOT * 2;   // 67,108,864
    const size_t wt_bytes = (size_t)N_TOT * K_TOT * 2;   // 33,554,432

    if (ws_size >= xb_bytes + wt_bytes) {
        __bf16* xb = (__bf16*)d_ws;
        __bf16* Wt = (__bf16*)((char*)d_ws + xb_bytes);
        const int cast_blocks = (M_TOT * K_TOT) / (256 * 8);   // 16384
        prep<<<dim3(4096 + cast_blocks), dim3(256), 0, stream>>>(
            x, qw, qz, sc, gi, xb, Wt);
        gemm8p<<<dim3((M_TOT / GBM) * (N_TOT / GBN)), dim3(512), 0, stream>>>(
            xb, Wt, bs, out);
    } else {
        gptq_gemm_fused<<<dim3(N_TOT / FBN, M_TOT / FBM), dim3(256), 0, stream>>>(
            x, qw, qz, sc, gi, bs, out);
    }
}

// Round 6
// 445.377 us; speedup vs baseline: 1.1010x; 1.0284x over previous
//
#include <hip/hip_runtime.h>
#include <hip/hip_bf16.h>
#include <stdint.h>

// Problem constants (fixed by setup_inputs)
#define M_TOT 8192
#define N_TOT 4096
#define K_TOT 4096
#define GROUP 128

// Round-2 lesson: fp16 reference arrays arrive as FLOAT32 ("else float*" rule).
// Round-4 lesson: fused one-pass is barrier/latency-bound; two-pass wins.
// Round-5 lesson: XOR chunk swizzle on global side of global_load_lds ->
//   0 LDS bank conflicts (measured).
// Round-6 lesson: 256^2 8-phase + counted vmcnt: 806 -> 1106 TF, MfmaUtil 49%
//   (gemm 249us). GOLDEN schedule -- restored verbatim below.
// Rounds 7-10 lessons (ALL REGRESSED, schedule ablation complete):
//   r7 mod-3 triple-buffer: 286us/42.5% (runtime LDS bases kill const-fold).
//   r9 no-lgkm0 + TAIL vmcnt: 280us/43.3% (lgkm drain was NOT the stall).
//   r10 deep A-prefetch ping-pong: 268us/45.1% (ph0 16-read entry cost ate
//     the prefetch gain). Conclusion: {vmcnt depth, lgkm drain, buffer count}
//     hypothesis space exhausted; r1 pattern is the measured optimum of this
//     structure. Do not perturb the K-loop further.
// Non-gemm time is 190-207us across ALL prep organizations (roofline ~45us):
//   harness reset/restore/launch overhead, not kernel-controllable.
// This round: r1 gemm verbatim + fused prep w/ nontemporal x loads (best
//   measured combination of the two halves).

using f32x4  = __attribute__((ext_vector_type(4))) float;
using bf16x8 = __attribute__((ext_vector_type(8))) __bf16;

typedef __attribute__((address_space(3))) void as3_void;
typedef const __attribute__((address_space(1))) void as1_void;

// ---------------- pass 1: fused prep (dequant blocks first, then cast) -------
// blocks [0, 4096):        dequant qweight -> Wt [N][K] bf16 (LDS transpose)
// blocks [4096, 20480):    cast x f32 -> bf16
__global__ __launch_bounds__(256) void prep(
    const float* __restrict__ x,
    const int*   __restrict__ qweight,  // [K/8, N]
    const int*   __restrict__ qzeros,   // [G, N/8]
    const float* __restrict__ scales,   // [G, N]
    const int*   __restrict__ g_idx,    // [K]
    __bf16* __restrict__ xb,            // [M, K]
    __bf16* __restrict__ Wt)            // [N, K]
{
    const int tid = threadIdx.x;
    if (blockIdx.x < 4096) {
        __shared__ __align__(16) unsigned short T[64 * 72];  // [64n][72k]
        const int k0 = (blockIdx.x & 63) * 64;
        const int n0 = (blockIdx.x >> 6) * 64;
        const int g  = g_idx[k0];       // 64-k tile sits in one group (64 | 128)

        #pragma unroll
        for (int i = 0; i < 2; ++i) {
            const int idx = tid + i * 256;  // 0..511
            const int r   = idx >> 6;       // 0..7  (8 k's each)
            const int n   = idx & 63;
            const int qi  = qweight[(size_t)((k0 >> 3) + r) * N_TOT + n0 + n];
            const int zi  = qzeros[g * (N_TOT / 8) + ((n0 + n) >> 3)];
            const float s = scales[g * N_TOT + n0 + n];
            const float zs = (float)(((zi >> ((n & 7) * 4)) & 0xF) + 1) * s;
            bf16x8 v;
            #pragma unroll
            for (int j = 0; j < 8; ++j)
                v[j] = (__bf16)((float)((qi >> (4 * j)) & 0xF) * s - zs);  // (w-z-1)*s
            *(bf16x8*)&T[n * 72 + r * 8] = v;
        }
        __syncthreads();

        const int n = tid >> 2;             // 0..63
        const int c = (tid & 3) * 16;       // 0,16,32,48
        const bf16x8 a = *(const bf16x8*)&T[n * 72 + c];
        const bf16x8 b = *(const bf16x8*)&T[n * 72 + c + 8];
        __bf16* dst = Wt + (size_t)(n0 + n) * K_TOT + k0 + c;
        *(bf16x8*)dst = a;
        *(bf16x8*)(dst + 8) = b;
    } else {
        const size_t t = (size_t)(blockIdx.x - 4096) * 256 + tid;
        // nontemporal: x is read exactly once; don't pollute L3.
        const f32x4 f0 = __builtin_nontemporal_load((const f32x4*)(x + t * 8));
        const f32x4 f1 = __builtin_nontemporal_load((const f32x4*)(x + t * 8) + 1);
        bf16x8 v;
        v[0]=(__bf16)f0.x; v[1]=(__bf16)f0.y; v[2]=(__bf16)f0.z; v[3]=(__bf16)f0.w;
        v[4]=(__bf16)f1.x; v[5]=(__bf16)f1.y; v[6]=(__bf16)f1.z; v[7]=(__bf16)f1.w;
        *(bf16x8*)(xb + t * 8) = v;
    }
}

// ------- pass 2: 256^2 8-phase bf16 GEMM (B^T), XOR-swizzled LDS -------
// r1 GOLDEN schedule, verbatim. Do not modify (see lessons above).
#define GBM 256
#define GBN 256
#define GBK 64
#define NKT (K_TOT / GBK)   // 64

#define BAR() do { asm volatile("" ::: "memory"); \
                   __builtin_amdgcn_s_barrier();  \
                   asm volatile("" ::: "memory"); } while (0)
#define WAIT_LGKM0() asm volatile("s_waitcnt lgkmcnt(0)" ::: "memory")
#define WAIT_VM4()   asm volatile("s_waitcnt vmcnt(4)"   ::: "memory")
#define WAIT_VM0()   asm volatile("s_waitcnt vmcnt(0)"   ::: "memory")

// Phase q (q=1..3): read A-quadrant, issue one half-tile stage, barrier,
// lgkmcnt(0), 16 MFMA under setprio(1), barrier.
#define GPHASE(q, STAGE_STMT)                                                 \
    {                                                                         \
        bf16x8 av[2][2];                                                      \
        _Pragma("unroll")                                                     \
        for (int ks = 0; ks < 2; ++ks) {                                      \
            av[0][ks] = ldA(buf, 2 * (q), ks);                                \
            av[1][ks] = ldA(buf, 2 * (q) + 1, ks);                            \
        }                                                                     \
        STAGE_STMT;                                                           \
        BAR();                                                                \
        WAIT_LGKM0();                                                         \
        __builtin_amdgcn_s_setprio(1);                                        \
        _Pragma("unroll")                                                     \
        for (int ks = 0; ks < 2; ++ks)                                        \
            _Pragma("unroll")                                                 \
            for (int mtl = 0; mtl < 2; ++mtl)                                 \
                _Pragma("unroll")                                             \
                for (int nt = 0; nt < 4; ++nt)                                \
                    acc[2 * (q) + mtl][nt] =                                  \
                        __builtin_amdgcn_mfma_f32_16x16x32_bf16(              \
                            av[mtl][ks], bv[nt][ks], acc[2 * (q) + mtl][nt],  \
                            0, 0, 0);                                         \
        __builtin_amdgcn_s_setprio(0);                                        \
        BAR();                                                                \
    }

__global__ __launch_bounds__(512, 2) void gemm8p(
    const __bf16* __restrict__ xb,   // [M, K]
    const __bf16* __restrict__ Wt,   // [N, K]
    const float*  __restrict__ bias, // [N]
    float* __restrict__ out)         // [M, N]
{
    // [buf][mat: 0=A,1=B][256 rows * 64 k] ushort = 128 KiB total
    __shared__ __align__(16) unsigned short LDS[2][2][GBM * GBK];

    const int tid  = threadIdx.x;
    const int wid  = tid >> 6;
    const int lane = tid & 63;
    const int l15  = lane & 15;
    const int quad = lane >> 4;

    // XCD-aware bijective swizzle (nwg = 512, divisible by 8)
    int bid = blockIdx.x;
    bid = (bid & 7) * (512 >> 3) + (bid >> 3);
    const int tn = bid & (N_TOT / GBN - 1);   // 0..15
    const int tm = bid >> 4;                  // 0..31
    const int m0 = tm * GBM;
    const int n0 = tn * GBN;

    const int wm = (wid >> 2) * 128;  // 0 or 128 (M-wave)
    const int wn = (wid & 3) * 64;    // 0..192   (N-wave)

    f32x4 acc[8][4];
    #pragma unroll
    for (int i = 0; i < 8; ++i)
        #pragma unroll
        for (int j = 0; j < 4; ++j)
            acc[i][j] = (f32x4)0.f;

    // Stage one half-tile (128 rows x 64 k) of mat into LDS[bf][mat], half h.
    // 2 x global_load_lds (16B) per thread. Chunk c holds global k-chunk
    // (c&7)^(row&7): LDS dst stays lane-linear, swizzle applied on global src.
    auto stage = [&](int bf, int mat, int h, const __bf16* __restrict__ base,
                     int row0, int kt) {
        #pragma unroll
        for (int j = 0; j < 2; ++j) {
            const int c  = j * 512 + tid;          // 0..1023 chunk id
            const int rl = c >> 3;                 // 0..127 row in half
            const int kc = (c & 7) ^ (rl & 7);     // XOR swizzle (global side)
            const __bf16* ga = base + (size_t)(row0 + h * 128 + rl) * K_TOT
                             + kt * GBK + kc * 8;
            __builtin_amdgcn_global_load_lds((as1_void*)ga,
                (as3_void*)&LDS[bf][mat][h * 8192 + (j * 512 + wid * 64) * 8],
                16, 0, 0);
        }
    };
    auto ldA = [&](int bf, int mt, int ks) -> bf16x8 {
        const int r = wm + mt * 16 + l15;
        return *(const bf16x8*)
            &LDS[bf][0][r * GBK + (((ks * 4 + quad) ^ (r & 7)) << 3)];
    };
    auto ldB = [&](int bf, int nt, int ks) -> bf16x8 {
        const int r = wn + nt * 16 + l15;
        return *(const bf16x8*)
            &LDS[bf][1][r * GBK + (((ks * 4 + quad) ^ (r & 7)) << 3)];
    };

    // Prologue: A(0),B(0) -> buf0; B(1) -> buf1. vmcnt(4) = A(0),B(0) landed,
    // B(1) (4 loads) still in flight.
    stage(0, 0, 0, xb, m0, 0); stage(0, 0, 1, xb, m0, 0);
    stage(0, 1, 0, Wt, n0, 0); stage(0, 1, 1, Wt, n0, 0);
    stage(1, 1, 0, Wt, n0, 1); stage(1, 1, 1, Wt, n0, 1);
    WAIT_VM4();
    BAR();

    bf16x8 bv[4][2];  // B frags held in regs across the whole K-tile

    for (int t = 0; t < NKT; ++t) {
        const int buf = t & 1;

        // ---- phase 0: all 8 B-frags + A quadrant 0 (12 ds_read_b128) ----
        {
            #pragma unroll
            for (int nt = 0; nt < 4; ++nt)
                #pragma unroll
                for (int ks = 0; ks < 2; ++ks)
                    bv[nt][ks] = ldB(buf, nt, ks);
            bf16x8 av[2][2];
            #pragma unroll
            for (int ks = 0; ks < 2; ++ks) {
                av[0][ks] = ldA(buf, 0, ks);
                av[1][ks] = ldA(buf, 1, ks);
            }
            if (t + 1 < NKT) stage(buf ^ 1, 0, 0, xb, m0, t + 1);
            BAR();
            WAIT_LGKM0();
            __builtin_amdgcn_s_setprio(1);
            #pragma unroll
            for (int ks = 0; ks < 2; ++ks)
                #pragma unroll
                for (int mtl = 0; mtl < 2; ++mtl)
                    #pragma unroll
                    for (int nt = 0; nt < 4; ++nt)
                        acc[mtl][nt] = __builtin_amdgcn_mfma_f32_16x16x32_bf16(
                            av[mtl][ks], bv[nt][ks], acc[mtl][nt], 0, 0, 0);
            __builtin_amdgcn_s_setprio(0);
            BAR();
        }
        // ---- phases 1-3: A quadrant + one half-tile stage each ----
        // B(t+2) -> buf is legal: B(t) in buf fully consumed at phase 0.
        GPHASE(1, if (t + 1 < NKT) stage(buf ^ 1, 0, 1, xb, m0, t + 1));
        GPHASE(2, if (t + 2 < NKT) stage(buf, 1, 0, Wt, n0, t + 2));
        GPHASE(3, if (t + 2 < NKT) stage(buf, 1, 1, Wt, n0, t + 2));

        // One counted wait per K-tile: leave B(t+2) (4 loads) in flight;
        // guarantees A(t+1) + everything older landed. Drain at the tail.
        if (t < NKT - 2) { WAIT_VM4(); } else { WAIT_VM0(); }
    }

    // epilogue: C/D layout col=lane&15, row=quad*4+reg (m89/m91-verified)
    #pragma unroll
    for (int nt = 0; nt < 4; ++nt) {
        const int col = n0 + wn + nt * 16 + l15;
        const float bb = bias[col];
        #pragma unroll
        for (int mt = 0; mt < 8; ++mt) {
            const int rowb = m0 + wm + mt * 16 + quad * 4;
            #pragma unroll
            for (int i = 0; i < 4; ++i)
                out[(size_t)(rowb + i) * N_TOT + col] = acc[mt][nt][i] + bb;
        }
    }
}

// ---------------- fallback: round-4 fused kernel (proven correct) ----------------
#define FBM 256
#define FBN 128
#define FBKP 72

__global__ __launch_bounds__(256, 2) void gptq_gemm_fused(
    const float* __restrict__ x, const int* __restrict__ qweight,
    const int* __restrict__ qzeros, const float* __restrict__ scales,
    const int* __restrict__ g_idx, const float* __restrict__ bias,
    float* __restrict__ out)
{
    __shared__ __align__(16) unsigned short As[FBM * FBKP];
    __shared__ __align__(16) unsigned short Bt[FBN * FBKP];

    const int tid  = threadIdx.x;
    const int wave = tid >> 6;
    const int lane = tid & 63;
    const int n0 = blockIdx.x * FBN;
    const int m0 = blockIdx.y * FBM;
    const int wm = (wave >> 1) * 64;
    const int wn = (wave & 1) * 64;
    const int l15  = lane & 15;
    const int quad = lane >> 4;

    f32x4 acc[2][4][4];
    #pragma unroll
    for (int mi = 0; mi < 2; ++mi)
        #pragma unroll
        for (int i = 0; i < 4; ++i)
            #pragma unroll
            for (int j = 0; j < 4; ++j)
                acc[mi][i][j] = (f32x4)0.f;

    const int nb  = tid & 31;
    const int r   = tid >> 5;
    const int zsh = (nb & 7) * 4;

    for (int kt = 0; kt < K_TOT / 64; ++kt) {
        const int k0 = kt * 64;
        #pragma unroll
        for (int i = 0; i < 8; ++i) {
            const int c   = tid + i * 256;
            const int row = c >> 3;
            const int cb  = (c & 7) << 3;
            const float* xp = x + (size_t)(m0 + row) * K_TOT + (k0 + cb);
            const float4 f0 = *(const float4*)xp;
            const float4 f1 = *(const float4*)(xp + 4);
            bf16x8 v;
            v[0]=(__bf16)f0.x; v[1]=(__bf16)f0.y; v[2]=(__bf16)f0.z; v[3]=(__bf16)f0.w;
            v[4]=(__bf16)f1.x; v[5]=(__bf16)f1.y; v[6]=(__bf16)f1.z; v[7]=(__bf16)f1.w;
            *(bf16x8*)&As[row * FBKP + cb] = v;
        }
        const int g    = g_idx[k0];
        const int qrow = (k0 >> 3) + r;
        #pragma unroll
        for (int dn = 0; dn < 4; ++dn) {
            const int n  = nb + dn * 32;
            const int qi = qweight[(size_t)qrow * N_TOT + (n0 + n)];
            const int zi = qzeros[g * (N_TOT / 8) + ((n0 + n) >> 3)];
            const float s = scales[g * N_TOT + (n0 + n)];
            const float zs = (float)(((zi >> zsh) & 0xF) + 1) * s;
            bf16x8 v;
            #pragma unroll
            for (int j = 0; j < 8; ++j)
                v[j] = (__bf16)((float)((qi >> (4 * j)) & 0xF) * s - zs);
            *(bf16x8*)&Bt[n * FBKP + r * 8] = v;
        }
        __syncthreads();
        #pragma unroll
        for (int ks = 0; ks < 2; ++ks) {
            bf16x8 bvv[4];
            #pragma unroll
            for (int nt = 0; nt < 4; ++nt)
                bvv[nt] = *(const bf16x8*)&Bt[(wn + nt * 16 + l15) * FBKP + ks * 32 + quad * 8];
            #pragma unroll
            for (int mi = 0; mi < 2; ++mi) {
                bf16x8 av[4];
                #pragma unroll
                for (int mt = 0; mt < 4; ++mt)
                    av[mt] = *(const bf16x8*)&As[(mi * 128 + wm + mt * 16 + l15) * FBKP + ks * 32 + quad * 8];
                #pragma unroll
                for (int mt = 0; mt < 4; ++mt)
                    #pragma unroll
                    for (int nt = 0; nt < 4; ++nt)
                        acc[mi][mt][nt] = __builtin_amdgcn_mfma_f32_16x16x32_bf16(
                            av[mt], bvv[nt], acc[mi][mt][nt], 0, 0, 0);
            }
        }
        __syncthreads();
    }
    #pragma unroll
    for (int mi = 0; mi < 2; ++mi)
        #pragma unroll
        for (int nt = 0; nt < 4; ++nt) {
            const int col = n0 + wn + nt * 16 + l15;
            const float bvv = bias[col];
            #pragma unroll
            for (int mt = 0; mt < 4; ++mt) {
                const int rowb = m0 + mi * 128 + wm + mt * 16 + quad * 4;
                #pragma unroll
                for (int i = 0; i < 4; ++i)
                    out[(size_t)(rowb + i) * N_TOT + col] = acc[mi][mt][nt][i] + bvv;
            }
        }
}

extern "C" void kernel_launch(void* const* d_in, const int* in_sizes, int n_in,
                              void* d_out, int out_size, void* d_ws, size_t ws_size,
                              hipStream_t stream) {
    const float* x  = (const float*)d_in[0];
    const int*   qw = (const int*)d_in[1];
    const int*   qz = (const int*)d_in[2];
    const float* sc = (const float*)d_in[3];
    const int*   gi = (const int*)d_in[4];
    const float* bs = (const float*)d_in[5];
    float* out = (float*)d_out;

    const size_t xb_bytes = (size_t)M_TOT * K_TOT * 2;   // 67,108,864
    const size_t wt_bytes = (size_t)N_TOT * K_TOT * 2;   // 33,554,432

    if (ws_size >= xb_bytes + wt_bytes) {
        __bf16* xb = (__bf16*)d_ws;
        __bf16* Wt = (__bf16*)((char*)d_ws + xb_bytes);
        const int cast_blocks = (M_TOT * K_TOT) / (256 * 8);   // 16384
        prep<<<dim3(4096 + cast_blocks), dim3(256), 0, stream>>>(
            x, qw, qz, sc, gi, xb, Wt);
        gemm8p<<<dim3((M_TOT / GBM) * (N_TOT / GBN)), dim3(512), 0, stream>>>(
            xb, Wt, bs, out);
    } else {
        gptq_gemm_fused<<<dim3(N_TOT / FBN, M_TOT / FBM), dim3(256), 0, stream>>>(
            x, qw, qz, sc, gi, bs, out);
    }
}

// Round 7
// 440.033 us; speedup vs baseline: 1.1144x; 1.0121x over previous
//
#include <hip/hip_runtime.h>
#include <hip/hip_bf16.h>
#include <stdint.h>

// Problem constants (fixed by setup_inputs)
#define M_TOT 8192
#define N_TOT 4096
#define K_TOT 4096
#define GROUP 128

// Round-2 lesson: fp16 reference arrays arrive as FLOAT32 ("else float*" rule).
// Round-4 lesson: fused one-pass is barrier/latency-bound; two-pass wins.
// Round-5 lesson: XOR chunk swizzle on global side of global_load_lds ->
//   0 LDS bank conflicts (measured).
// Round-6 lesson: 256^2 8-phase + counted vmcnt: gemm 249us/49% (GOLDEN).
// Rounds 7-10 (ALL REGRESSED): mod-3 buffers (286/42.5 - runtime LDS bases),
//   no-lgkm0+TAIL vmcnt (280/43.3), deep A-prefetch (268/45.1). Schedule
//   hypothesis space {vmcnt depth, lgkm drain, buffer count} exhausted.
// Round-11 lesson: r1 restored reproduces 245-247us/50% -> config stable.
// Round-12 (this round): finish the m201 template port at CODEGEN level,
//   schedule untouched: (1) 2 K-tiles/iter manual unroll -> literal buf,
//   all LDS addrs compile-const (r7 showed runtime bases cost ~13%);
//   (2) pre-barrier lgkmcnt(8) at the 12-read phase 0 (m201 detail);
//   (3) hoisted per-thread global stage bases (row-mul/swizzle invariant).

using f32x4  = __attribute__((ext_vector_type(4))) float;
using bf16x8 = __attribute__((ext_vector_type(8))) __bf16;

typedef __attribute__((address_space(3))) void as3_void;
typedef const __attribute__((address_space(1))) void as1_void;

// ---------------- pass 1: fused prep (dequant blocks first, then cast) -------
// blocks [0, 4096):        dequant qweight -> Wt [N][K] bf16 (LDS transpose)
// blocks [4096, 20480):    cast x f32 -> bf16
__global__ __launch_bounds__(256) void prep(
    const float* __restrict__ x,
    const int*   __restrict__ qweight,  // [K/8, N]
    const int*   __restrict__ qzeros,   // [G, N/8]
    const float* __restrict__ scales,   // [G, N]
    const int*   __restrict__ g_idx,    // [K]
    __bf16* __restrict__ xb,            // [M, K]
    __bf16* __restrict__ Wt)            // [N, K]
{
    const int tid = threadIdx.x;
    if (blockIdx.x < 4096) {
        __shared__ __align__(16) unsigned short T[64 * 72];  // [64n][72k]
        const int k0 = (blockIdx.x & 63) * 64;
        const int n0 = (blockIdx.x >> 6) * 64;
        const int g  = g_idx[k0];       // 64-k tile sits in one group (64 | 128)

        #pragma unroll
        for (int i = 0; i < 2; ++i) {
            const int idx = tid + i * 256;  // 0..511
            const int r   = idx >> 6;       // 0..7  (8 k's each)
            const int n   = idx & 63;
            const int qi  = qweight[(size_t)((k0 >> 3) + r) * N_TOT + n0 + n];
            const int zi  = qzeros[g * (N_TOT / 8) + ((n0 + n) >> 3)];
            const float s = scales[g * N_TOT + n0 + n];
            const float zs = (float)(((zi >> ((n & 7) * 4)) & 0xF) + 1) * s;
            bf16x8 v;
            #pragma unroll
            for (int j = 0; j < 8; ++j)
                v[j] = (__bf16)((float)((qi >> (4 * j)) & 0xF) * s - zs);  // (w-z-1)*s
            *(bf16x8*)&T[n * 72 + r * 8] = v;
        }
        __syncthreads();

        const int n = tid >> 2;             // 0..63
        const int c = (tid & 3) * 16;       // 0,16,32,48
        const bf16x8 a = *(const bf16x8*)&T[n * 72 + c];
        const bf16x8 b = *(const bf16x8*)&T[n * 72 + c + 8];
        __bf16* dst = Wt + (size_t)(n0 + n) * K_TOT + k0 + c;
        *(bf16x8*)dst = a;
        *(bf16x8*)(dst + 8) = b;
    } else {
        const size_t t = (size_t)(blockIdx.x - 4096) * 256 + tid;
        // nontemporal: x is read exactly once; don't pollute L3.
        const f32x4 f0 = __builtin_nontemporal_load((const f32x4*)(x + t * 8));
        const f32x4 f1 = __builtin_nontemporal_load((const f32x4*)(x + t * 8) + 1);
        bf16x8 v;
        v[0]=(__bf16)f0.x; v[1]=(__bf16)f0.y; v[2]=(__bf16)f0.z; v[3]=(__bf16)f0.w;
        v[4]=(__bf16)f1.x; v[5]=(__bf16)f1.y; v[6]=(__bf16)f1.z; v[7]=(__bf16)f1.w;
        *(bf16x8*)(xb + t * 8) = v;
    }
}

// ------- pass 2: 256^2 8-phase bf16 GEMM (B^T), XOR-swizzled LDS -------
// r1 GOLDEN schedule (barrier/wait/stage placement identical); round-12
// adds only codegen-level changes: 2-tile unroll, lgkm8 pre-drain, hoisted
// global bases.
#define GBM 256
#define GBN 256
#define GBK 64
#define NKT (K_TOT / GBK)   // 64

#define BAR() do { asm volatile("" ::: "memory"); \
                   __builtin_amdgcn_s_barrier();  \
                   asm volatile("" ::: "memory"); } while (0)
#define WAIT_LGKM0() asm volatile("s_waitcnt lgkmcnt(0)" ::: "memory")
#define WAIT_LGKM8() asm volatile("s_waitcnt lgkmcnt(8)" ::: "memory")
#define WAIT_VM4()   asm volatile("s_waitcnt vmcnt(4)"   ::: "memory")
#define WAIT_VM0()   asm volatile("s_waitcnt vmcnt(0)"   ::: "memory")

// 16 MFMA into acc[base..base+1][0..3] from av (in scope) x bv.
#define MFMA8(base)                                                           \
    _Pragma("unroll")                                                         \
    for (int ks = 0; ks < 2; ++ks)                                            \
        _Pragma("unroll")                                                     \
        for (int mtl = 0; mtl < 2; ++mtl)                                     \
            _Pragma("unroll")                                                 \
            for (int nt = 0; nt < 4; ++nt)                                    \
                acc[(base) + mtl][nt] =                                       \
                    __builtin_amdgcn_mfma_f32_16x16x32_bf16(                  \
                        av[mtl][ks], bv[nt][ks], acc[(base) + mtl][nt],       \
                        0, 0, 0);

// Phase q (q=1..3): read A-quadrant (literal BUF), issue stage, barrier,
// lgkmcnt(0), 16 MFMA under setprio(1), barrier.  (r1 pattern.)
#define PHASE_Q(BUF, q, STAGE_STMT)                                           \
    {                                                                         \
        bf16x8 av[2][2];                                                      \
        _Pragma("unroll")                                                     \
        for (int ks = 0; ks < 2; ++ks) {                                      \
            av[0][ks] = ldA(BUF, 2 * (q), ks);                                \
            av[1][ks] = ldA(BUF, 2 * (q) + 1, ks);                            \
        }                                                                     \
        STAGE_STMT;                                                           \
        BAR();                                                                \
        WAIT_LGKM0();                                                         \
        __builtin_amdgcn_s_setprio(1);                                        \
        MFMA8(2 * (q));                                                       \
        __builtin_amdgcn_s_setprio(0);                                        \
        BAR();                                                                \
    }

// One K-tile, literal buffer index BUF. Phase 0: 8 B-frags + A quadrant 0
// (12 ds_read_b128) with lgkmcnt(8) pre-drain before the barrier (m201).
#define KTILE(BUF, SA0, SA1, SB2, SB3, TAILW)                                 \
    {                                                                         \
        _Pragma("unroll")                                                     \
        for (int nt = 0; nt < 4; ++nt)                                        \
            _Pragma("unroll")                                                 \
            for (int ks = 0; ks < 2; ++ks)                                    \
                bv[nt][ks] = ldB(BUF, nt, ks);                                \
        {                                                                     \
            bf16x8 av[2][2];                                                  \
            _Pragma("unroll")                                                 \
            for (int ks = 0; ks < 2; ++ks) {                                  \
                av[0][ks] = ldA(BUF, 0, ks);                                  \
                av[1][ks] = ldA(BUF, 1, ks);                                  \
            }                                                                 \
            SA0;                                                              \
            WAIT_LGKM8();                                                     \
            BAR();                                                            \
            WAIT_LGKM0();                                                     \
            __builtin_amdgcn_s_setprio(1);                                    \
            MFMA8(0);                                                         \
            __builtin_amdgcn_s_setprio(0);                                    \
            BAR();                                                            \
        }                                                                     \
        PHASE_Q(BUF, 1, SA1);                                                 \
        PHASE_Q(BUF, 2, SB2);                                                 \
        PHASE_Q(BUF, 3, SB3);                                                 \
        TAILW;                                                                \
    }

__global__ __launch_bounds__(512, 2) void gemm8p(
    const __bf16* __restrict__ xb,   // [M, K]
    const __bf16* __restrict__ Wt,   // [N, K]
    const float*  __restrict__ bias, // [N]
    float* __restrict__ out)         // [M, N]
{
    // [buf][mat: 0=A,1=B][256 rows * 64 k] ushort = 128 KiB total
    __shared__ __align__(16) unsigned short LDS[2][2][GBM * GBK];

    const int tid  = threadIdx.x;
    const int wid  = tid >> 6;
    const int lane = tid & 63;
    const int l15  = lane & 15;
    const int quad = lane >> 4;

    // XCD-aware bijective swizzle (nwg = 512, divisible by 8)
    int bid = blockIdx.x;
    bid = (bid & 7) * (512 >> 3) + (bid >> 3);
    const int tn = bid & (N_TOT / GBN - 1);   // 0..15
    const int tm = bid >> 4;                  // 0..31
    const int m0 = tm * GBM;
    const int n0 = tn * GBN;

    const int wm = (wid >> 2) * 128;  // 0 or 128 (M-wave)
    const int wn = (wid & 3) * 64;    // 0..192   (N-wave)

    f32x4 acc[8][4];
    #pragma unroll
    for (int i = 0; i < 8; ++i)
        #pragma unroll
        for (int j = 0; j < 4; ++j)
            acc[i][j] = (f32x4)0.f;

    // Hoisted per-thread global stage bases. In the original indexing:
    // c = j*512+tid -> rl = j*64 + (tid>>3); kc = (tid&7) ^ (rl&7) and
    // rl&7 == (tid>>3)&7 for all j (j*64 = 0 mod 8). So the per-thread
    // row/swizzle term is loop-invariant; j and h become constant offsets.
    const int rl0 = tid >> 3;                       // 0..63
    const int kc0 = (tid & 7) ^ (rl0 & 7);          // XOR swizzle (global side)
    const __bf16* gA = xb + (size_t)(m0 + rl0) * K_TOT + kc0 * 8;
    const __bf16* gB = Wt + (size_t)(n0 + rl0) * K_TOT + kc0 * 8;

    // Stage one half-tile (128 rows x 64 k) into LDS[bf][mat], half h.
    // 2 x global_load_lds (16B)/thread; gbase is the hoisted per-thread base.
    auto stage = [&](int bf, int mat, int h, const __bf16* gbase, int kt) {
        #pragma unroll
        for (int j = 0; j < 2; ++j) {
            const __bf16* ga = gbase
                + (size_t)(h * 128 + j * 64) * K_TOT + kt * GBK;
            __builtin_amdgcn_global_load_lds((as1_void*)ga,
                (as3_void*)&LDS[bf][mat][h * 8192 + (j * 512 + wid * 64) * 8],
                16, 0, 0);
        }
    };
    auto ldA = [&](int bf, int mt, int ks) -> bf16x8 {
        const int r = wm + mt * 16 + l15;
        return *(const bf16x8*)
            &LDS[bf][0][r * GBK + (((ks * 4 + quad) ^ (r & 7)) << 3)];
    };
    auto ldB = [&](int bf, int nt, int ks) -> bf16x8 {
        const int r = wn + nt * 16 + l15;
        return *(const bf16x8*)
            &LDS[bf][1][r * GBK + (((ks * 4 + quad) ^ (r & 7)) << 3)];
    };

    // Prologue: A(0),B(0) -> buf0; B(1) -> buf1. vmcnt(4) = A(0),B(0) landed,
    // B(1) (4 loads) still in flight.
    stage(0, 0, 0, gA, 0); stage(0, 0, 1, gA, 0);
    stage(0, 1, 0, gB, 0); stage(0, 1, 1, gB, 0);
    stage(1, 1, 0, gB, 1); stage(1, 1, 1, gB, 1);
    WAIT_VM4();
    BAR();

    bf16x8 bv[4][2];  // B frags held in regs across the whole K-tile

    // 2 K-tiles per iteration (m201: 8 phases/iter) -> literal buf indices.
    // Stage slots and waits are r1-verbatim per tile:
    //   ph0/ph1: A(t+1) -> other buf; ph2/ph3: B(t+2) -> same buf;
    //   end-of-tile: vmcnt(4) (B(t+2) in flight), vmcnt(0) at the tail.
    for (int tt = 0; tt < NKT / 2; ++tt) {
        const int t0 = 2 * tt, t1 = 2 * tt + 1;
        const bool last = (tt == NKT / 2 - 1);

        KTILE(0,
              stage(1, 0, 0, gA, t0 + 1),
              stage(1, 0, 1, gA, t0 + 1),
              if (!last) stage(0, 1, 0, gB, t0 + 2),
              if (!last) stage(0, 1, 1, gB, t0 + 2),
              if (!last) { WAIT_VM4(); } else { WAIT_VM0(); });

        KTILE(1,
              if (!last) stage(0, 0, 0, gA, t1 + 1),
              if (!last) stage(0, 0, 1, gA, t1 + 1),
              if (!last) stage(1, 1, 0, gB, t1 + 2),
              if (!last) stage(1, 1, 1, gB, t1 + 2),
              if (!last) { WAIT_VM4(); } else { WAIT_VM0(); });
    }

    // epilogue: C/D layout col=lane&15, row=quad*4+reg (m89/m91-verified)
    #pragma unroll
    for (int nt = 0; nt < 4; ++nt) {
        const int col = n0 + wn + nt * 16 + l15;
        const float bb = bias[col];
        #pragma unroll
        for (int mt = 0; mt < 8; ++mt) {
            const int rowb = m0 + wm + mt * 16 + quad * 4;
            #pragma unroll
            for (int i = 0; i < 4; ++i)
                out[(size_t)(rowb + i) * N_TOT + col] = acc[mt][nt][i] + bb;
        }
    }
}

// ---------------- fallback: round-4 fused kernel (proven correct) ----------------
#define FBM 256
#define FBN 128
#define FBKP 72

__global__ __launch_bounds__(256, 2) void gptq_gemm_fused(
    const float* __restrict__ x, const int* __restrict__ qweight,
    const int* __restrict__ qzeros, const float* __restrict__ scales,
    const int* __restrict__ g_idx, const float* __restrict__ bias,
    float* __restrict__ out)
{
    __shared__ __align__(16) unsigned short As[FBM * FBKP];
    __shared__ __align__(16) unsigned short Bt[FBN * FBKP];

    const int tid  = threadIdx.x;
    const int wave = tid >> 6;
    const int lane = tid & 63;
    const int n0 = blockIdx.x * FBN;
    const int m0 = blockIdx.y * FBM;
    const int wm = (wave >> 1) * 64;
    const int wn = (wave & 1) * 64;
    const int l15  = lane & 15;
    const int quad = lane >> 4;

    f32x4 acc[2][4][4];
    #pragma unroll
    for (int mi = 0; mi < 2; ++mi)
        #pragma unroll
        for (int i = 0; i < 4; ++i)
            #pragma unroll
            for (int j = 0; j < 4; ++j)
                acc[mi][i][j] = (f32x4)0.f;

    const int nb  = tid & 31;
    const int r   = tid >> 5;
    const int zsh = (nb & 7) * 4;

    for (int kt = 0; kt < K_TOT / 64; ++kt) {
        const int k0 = kt * 64;
        #pragma unroll
        for (int i = 0; i < 8; ++i) {
            const int c   = tid + i * 256;
            const int row = c >> 3;
            const int cb  = (c & 7) << 3;
            const float* xp = x + (size_t)(m0 + row) * K_TOT + (k0 + cb);
            const float4 f0 = *(const float4*)xp;
            const float4 f1 = *(const float4*)(xp + 4);
            bf16x8 v;
            v[0]=(__bf16)f0.x; v[1]=(__bf16)f0.y; v[2]=(__bf16)f0.z; v[3]=(__bf16)f0.w;
            v[4]=(__bf16)f1.x; v[5]=(__bf16)f1.y; v[6]=(__bf16)f1.z; v[7]=(__bf16)f1.w;
            *(bf16x8*)&As[row * FBKP + cb] = v;
        }
        const int g    = g_idx[k0];
        const int qrow = (k0 >> 3) + r;
        #pragma unroll
        for (int dn = 0; dn < 4; ++dn) {
            const int n  = nb + dn * 32;
            const int qi = qweight[(size_t)qrow * N_TOT + (n0 + n)];
            const int zi = qzeros[g * (N_TOT / 8) + ((n0 + n) >> 3)];
            const float s = scales[g * N_TOT + (n0 + n)];
            const float zs = (float)(((zi >> zsh) & 0xF) + 1) * s;
            bf16x8 v;
            #pragma unroll
            for (int j = 0; j < 8; ++j)
                v[j] = (__bf16)((float)((qi >> (4 * j)) & 0xF) * s - zs);
            *(bf16x8*)&Bt[n * FBKP + r * 8] = v;
        }
        __syncthreads();
        #pragma unroll
        for (int ks = 0; ks < 2; ++ks) {
            bf16x8 bvv[4];
            #pragma unroll
            for (int nt = 0; nt < 4; ++nt)
                bvv[nt] = *(const bf16x8*)&Bt[(wn + nt * 16 + l15) * FBKP + ks * 32 + quad * 8];
            #pragma unroll
            for (int mi = 0; mi < 2; ++mi) {
                bf16x8 av[4];
                #pragma unroll
                for (int mt = 0; mt < 4; ++mt)
                    av[mt] = *(const bf16x8*)&As[(mi * 128 + wm + mt * 16 + l15) * FBKP + ks * 32 + quad * 8];
                #pragma unroll
                for (int mt = 0; mt < 4; ++mt)
                    #pragma unroll
                    for (int nt = 0; nt < 4; ++nt)
                        acc[mi][mt][nt] = __builtin_amdgcn_mfma_f32_16x16x32_bf16(
                            av[mt], bvv[nt], acc[mi][mt][nt], 0, 0, 0);
            }
        }
        __syncthreads();
    }
    #pragma unroll
    for (int mi = 0; mi < 2; ++mi)
        #pragma unroll
        for (int nt = 0; nt < 4; ++nt) {
            const int col = n0 + wn + nt * 16 + l15;
            const float bvv = bias[col];
            #pragma unroll
            for (int mt = 0; mt < 4; ++mt) {
                const int rowb = m0 + mi * 128 + wm + mt * 16 + quad * 4;
                #pragma unroll
                for (int i = 0; i < 4; ++i)
                    out[(size_t)(rowb + i) * N_TOT + col] = acc[mi][mt][nt][i] + bvv;
            }
        }
}

extern "C" void kernel_launch(void* const* d_in, const int* in_sizes, int n_in,
                              void* d_out, int out_size, void* d_ws, size_t ws_size,
                              hipStream_t stream) {
    const float* x  = (const float*)d_in[0];
    const int*   qw = (const int*)d_in[1];
    const int*   qz = (const int*)d_in[2];
    const float* sc = (const float*)d_in[3];
    const int*   gi = (const int*)d_in[4];
    const float* bs = (const float*)d_in[5];
    float* out = (float*)d_out;

    const size_t xb_bytes = (size_t)M_TOT * K_TOT * 2;   // 67,108,864
    const size_t wt_bytes = (size_t)N_TOT * K_TOT * 2;   // 33,554,432

    if (ws_size >= xb_bytes + wt_bytes) {
        __bf16* xb = (__bf16*)d_ws;
        __bf16* Wt = (__bf16*)((char*)d_ws + xb_bytes);
        const int cast_blocks = (M_TOT * K_TOT) / (256 * 8);   // 16384
        prep<<<dim3(4096 + cast_blocks), dim3(256), 0, stream>>>(
            x, qw, qz, sc, gi, xb, Wt);
        gemm8p<<<dim3((M_TOT / GBM) * (N_TOT / GBN)), dim3(512), 0, stream>>>(
            xb, Wt, bs, out);
    } else {
        gptq_gemm_fused<<<dim3(N_TOT / FBN, M_TOT / FBM), dim3(256), 0, stream>>>(
            x, qw, qz, sc, gi, bs, out);
    }
}